// Round 1
// baseline (7732.298 us; speedup 1.0000x reference)
//
#include <hip/hip_runtime.h>
#include <hip/hip_bf16.h>

// Problem: B=64, T=1024, INPUT=256, HIDDEN=512, OUTPUT=256
//   xh = x @ W_xh + b_h          [65536,256]@[256,512]
//   h_t = tanh(h_{t-1} @ W_hh + xh_t)   (serial over t)
//   out = hs @ W_hy + b_y        [65536,512]@[512,256]

#define BT 65536      // B*T
#define HID 512
#define NIN 256
#define NOUT 256
#define TSTEPS 1024
#define NBATCH 64

// ---------- helpers ----------
__device__ __forceinline__ float bf16lo(unsigned int u) {
    return __uint_as_float(u << 16);
}
__device__ __forceinline__ float bf16hi(unsigned int u) {
    return __uint_as_float(u & 0xffff0000u);
}
__device__ __forceinline__ float b2f(__hip_bfloat16 h) {
    return __bfloat162float(h);
}

__device__ __forceinline__ float4 load4f(const float* p) {
    return *(const float4*)p;
}
__device__ __forceinline__ float4 load4f(const __hip_bfloat16* p) {
    ushort4 u = *(const ushort4*)p;
    float4 r;
    r.x = __uint_as_float(((unsigned int)u.x) << 16);
    r.y = __uint_as_float(((unsigned int)u.y) << 16);
    r.z = __uint_as_float(((unsigned int)u.z) << 16);
    r.w = __uint_as_float(((unsigned int)u.w) << 16);
    return r;
}

__device__ __forceinline__ void store1(float* p, float v) { *p = v; }
__device__ __forceinline__ void store1(__hip_bfloat16* p, float v) {
    *p = __float2bfloat16(v);
}

// ---------- pack W_hh (f32 [k][j]) -> bf16 grouped layout [k/8][j][k%8] ----------
// so the scan can read 8 consecutive-k weights for its column j with one 16B load.
__global__ __launch_bounds__(512)
void pack_whh_kernel(const float* __restrict__ W, __hip_bfloat16* __restrict__ Wp) {
    int k = blockIdx.x;      // 0..511
    int j = threadIdx.x;     // 0..511
    float v = W[k * HID + j];
    Wp[(size_t)(k >> 3) * (HID * 8) + j * 8 + (k & 7)] = __float2bfloat16(v);
}

// ---------- generic tiled GEMM with bias: C[M,N] = A[M,K] @ B[K,N] + bias[N] ----------
// 256 threads, 64x64 tile, each thread a 4x4 microtile, TK=16 staged in LDS.
template <typename AT, typename CT>
__global__ __launch_bounds__(256)
void gemm_bias_kernel(const AT* __restrict__ A, const float* __restrict__ B,
                      const float* __restrict__ bias, CT* __restrict__ C,
                      int M, int N, int K) {
    const int TM = 64, TN = 64, TK = 16;
    __shared__ float As[TK][TM];       // [k][m]
    __shared__ float Bs[TK][TN + 4];   // [k][n], +4 pad keeps 16B alignment (68*4=272)

    int tid = threadIdx.x;
    int tx = tid & 15;   // 0..15 -> col group
    int ty = tid >> 4;   // 0..15 -> row group
    int row0 = blockIdx.x * TM;
    int col0 = blockIdx.y * TN;

    float c[4][4];
#pragma unroll
    for (int i = 0; i < 4; ++i)
#pragma unroll
        for (int j = 0; j < 4; ++j) c[i][j] = 0.f;

    for (int kk = 0; kk < K; kk += TK) {
        // A tile: 64 rows x 16 k. thread -> row = tid>>2, kcol = (tid&3)*4
        {
            int ar = tid >> 2;
            int ac = (tid & 3) * 4;
            float4 av = load4f(A + (size_t)(row0 + ar) * K + kk + ac);
            As[ac + 0][ar] = av.x;
            As[ac + 1][ar] = av.y;
            As[ac + 2][ar] = av.z;
            As[ac + 3][ar] = av.w;
        }
        // B tile: 16 k-rows x 64 cols. thread -> krow = tid>>4, col = (tid&15)*4
        {
            int br = tid >> 4;
            int bc = (tid & 15) * 4;
            float4 bv = *(const float4*)(B + (size_t)(kk + br) * N + col0 + bc);
            *(float4*)&Bs[br][bc] = bv;
        }
        __syncthreads();
#pragma unroll
        for (int k = 0; k < TK; ++k) {
            float4 a = *(const float4*)&As[k][ty * 4];
            float4 b = *(const float4*)&Bs[k][tx * 4];
            float av[4] = {a.x, a.y, a.z, a.w};
            float bv[4] = {b.x, b.y, b.z, b.w};
#pragma unroll
            for (int i = 0; i < 4; ++i)
#pragma unroll
                for (int j = 0; j < 4; ++j) c[i][j] += av[i] * bv[j];
        }
        __syncthreads();
    }

    // epilogue: bias + store
#pragma unroll
    for (int j = 0; j < 4; ++j) {
        float bb = bias[col0 + tx * 4 + j];
#pragma unroll
        for (int i = 0; i < 4; ++i) {
            int r = row0 + ty * 4 + i;
            int cc = col0 + tx * 4 + j;
            store1(&C[(size_t)r * N + cc], c[i][j] + bb);
        }
    }
}

// ---------- sequential recurrence: one workgroup per batch row ----------
// h kept in f32 double-buffered LDS; W_hh read as packed bf16 (16B per 8 k's).
__global__ __launch_bounds__(512)
void rnn_scan_kernel(const __hip_bfloat16* __restrict__ xh,
                     const uint4* __restrict__ Wp,   // [64 groups][512 cols] of 8 bf16
                     __hip_bfloat16* __restrict__ hs) {
    __shared__ float h[2][HID];
    const int b = blockIdx.x;
    const int j = threadIdx.x;

    h[0][j] = 0.f;
    __syncthreads();

    const uint4* wcol = Wp + j;                 // stride per k-group: HID entries
    size_t base = (size_t)b * TSTEPS * HID + j;
    int cur = 0;

    for (int t = 0; t < TSTEPS; ++t) {
        float acc = b2f(xh[base + (size_t)t * HID]);
        const float* hc = h[cur];
#pragma unroll 8
        for (int g = 0; g < 64; ++g) {
            uint4 w = wcol[(size_t)g * HID];
            float4 h0 = *(const float4*)(hc + g * 8);
            float4 h1 = *(const float4*)(hc + g * 8 + 4);
            acc += h0.x * bf16lo(w.x);
            acc += h0.y * bf16hi(w.x);
            acc += h0.z * bf16lo(w.y);
            acc += h0.w * bf16hi(w.y);
            acc += h1.x * bf16lo(w.z);
            acc += h1.y * bf16hi(w.z);
            acc += h1.z * bf16lo(w.w);
            acc += h1.w * bf16hi(w.w);
        }
        float hn = tanhf(acc);
        h[cur ^ 1][j] = hn;
        hs[base + (size_t)t * HID] = __float2bfloat16(hn);
        cur ^= 1;
        __syncthreads();
    }
}

extern "C" void kernel_launch(void* const* d_in, const int* in_sizes, int n_in,
                              void* d_out, int out_size, void* d_ws, size_t ws_size,
                              hipStream_t stream) {
    const float* x    = (const float*)d_in[0];   // [64,1024,256]
    const float* W_xh = (const float*)d_in[1];   // [256,512]
    const float* W_hh = (const float*)d_in[2];   // [512,512]
    const float* b_h  = (const float*)d_in[3];   // [512]
    const float* W_hy = (const float*)d_in[4];   // [512,256]
    const float* b_y  = (const float*)d_in[5];   // [256]
    float* out = (float*)d_out;                  // [64,1024,256]

    char* ws = (char*)d_ws;
    __hip_bfloat16* Wp = (__hip_bfloat16*)ws;                       // 512 KB packed W_hh
    __hip_bfloat16* xh = (__hip_bfloat16*)(ws + (1 << 20));         // 64 MiB
    __hip_bfloat16* hs = (__hip_bfloat16*)(ws + (1 << 20) + (size_t)BT * HID * 2);  // 64 MiB

    // 1) pack W_hh -> bf16 grouped layout
    pack_whh_kernel<<<dim3(HID), dim3(HID), 0, stream>>>(W_hh, Wp);

    // 2) xh = x @ W_xh + b_h   (f32 A -> bf16 C)
    gemm_bias_kernel<float, __hip_bfloat16>
        <<<dim3(BT / 64, HID / 64), dim3(256), 0, stream>>>(x, W_xh, b_h, xh, BT, HID, NIN);

    // 3) serial scan over time, one WG per batch row
    rnn_scan_kernel<<<dim3(NBATCH), dim3(HID), 0, stream>>>(xh, (const uint4*)Wp, hs);

    // 4) out = hs @ W_hy + b_y   (bf16 A -> f32 C)
    gemm_bias_kernel<__hip_bfloat16, float>
        <<<dim3(BT / 64, NOUT / 64), dim3(256), 0, stream>>>(hs, W_hy, b_y, out, BT, NOUT, HID);
}

// Round 2
// 6858.873 us; speedup vs baseline: 1.1273x; 1.1273x over previous
//
#include <hip/hip_runtime.h>
#include <hip/hip_bf16.h>

// Problem: B=64, T=1024, INPUT=256, HIDDEN=512, OUTPUT=256
//   xh = x @ W_xh + b_h
//   h_t = tanh(h_{t-1} @ W_hh + xh_t)   (serial over t)
//   out = hs @ W_hy + b_y

#define BT 65536      // B*T
#define HID 512
#define NIN 256
#define NOUT 256
#define TSTEPS 1024
#define NBATCH 64
#define PSPLIT 4
#define JSLICE 128    // HID / PSPLIT

// ---------- helpers ----------
__device__ __forceinline__ float bf16lo(unsigned int u) {
    return __uint_as_float(u << 16);
}
__device__ __forceinline__ float bf16hi(unsigned int u) {
    return __uint_as_float(u & 0xffff0000u);
}
__device__ __forceinline__ unsigned bf16bits(float f) {
    __hip_bfloat16 h = __float2bfloat16(f);
    unsigned short u;
    __builtin_memcpy(&u, &h, 2);
    return (unsigned)u;
}

__device__ __forceinline__ float4 load4f(const float* p) {
    return *(const float4*)p;
}
__device__ __forceinline__ float4 load4f(const __hip_bfloat16* p) {
    ushort4 u = *(const ushort4*)p;
    float4 r;
    r.x = __uint_as_float(((unsigned int)u.x) << 16);
    r.y = __uint_as_float(((unsigned int)u.y) << 16);
    r.z = __uint_as_float(((unsigned int)u.z) << 16);
    r.w = __uint_as_float(((unsigned int)u.w) << 16);
    return r;
}

__device__ __forceinline__ void store1(float* p, float v) { *p = v; }
__device__ __forceinline__ void store1(__hip_bfloat16* p, float v) {
    *p = __float2bfloat16(v);
}

// ---------- pack W_hh (f32 [k][j]) -> bf16 grouped layout [k/8][j][k%8] ----------
__global__ __launch_bounds__(512)
void pack_whh_kernel(const float* __restrict__ W, __hip_bfloat16* __restrict__ Wp) {
    int k = blockIdx.x;      // 0..511
    int j = threadIdx.x;     // 0..511
    float v = W[k * HID + j];
    Wp[(size_t)(k >> 3) * (HID * 8) + j * 8 + (k & 7)] = __float2bfloat16(v);
}

// ---------- generic tiled GEMM with bias: C[M,N] = A[M,K] @ B[K,N] + bias[N] ----------
template <typename AT, typename CT>
__global__ __launch_bounds__(256)
void gemm_bias_kernel(const AT* __restrict__ A, const float* __restrict__ B,
                      const float* __restrict__ bias, CT* __restrict__ C,
                      int M, int N, int K) {
    const int TM = 64, TN = 64, TK = 16;
    __shared__ float As[TK][TM];
    __shared__ float Bs[TK][TN + 4];

    int tid = threadIdx.x;
    int tx = tid & 15;
    int ty = tid >> 4;
    int row0 = blockIdx.x * TM;
    int col0 = blockIdx.y * TN;

    float c[4][4];
#pragma unroll
    for (int i = 0; i < 4; ++i)
#pragma unroll
        for (int j = 0; j < 4; ++j) c[i][j] = 0.f;

    for (int kk = 0; kk < K; kk += TK) {
        {
            int ar = tid >> 2;
            int ac = (tid & 3) * 4;
            float4 av = load4f(A + (size_t)(row0 + ar) * K + kk + ac);
            As[ac + 0][ar] = av.x;
            As[ac + 1][ar] = av.y;
            As[ac + 2][ar] = av.z;
            As[ac + 3][ar] = av.w;
        }
        {
            int br = tid >> 4;
            int bc = (tid & 15) * 4;
            float4 bv = *(const float4*)(B + (size_t)(kk + br) * N + col0 + bc);
            *(float4*)&Bs[br][bc] = bv;
        }
        __syncthreads();
#pragma unroll
        for (int k = 0; k < TK; ++k) {
            float4 a = *(const float4*)&As[k][ty * 4];
            float4 b = *(const float4*)&Bs[k][tx * 4];
            float av[4] = {a.x, a.y, a.z, a.w};
            float bv[4] = {b.x, b.y, b.z, b.w};
#pragma unroll
            for (int i = 0; i < 4; ++i)
#pragma unroll
                for (int j = 0; j < 4; ++j) c[i][j] += av[i] * bv[j];
        }
        __syncthreads();
    }

#pragma unroll
    for (int j = 0; j < 4; ++j) {
        float bb = bias[col0 + tx * 4 + j];
#pragma unroll
        for (int i = 0; i < 4; ++i) {
            int r = row0 + ty * 4 + i;
            int cc = col0 + tx * 4 + j;
            store1(&C[(size_t)r * N + cc], c[i][j] + bb);
        }
    }
}

// ---------- persistent scan: 256 WGs = 64 rows x 4 hidden-slices ----------
// W slice lives in registers (128 f32/thread). h exchanged through hs (agent-
// scope atomics -> coherent point) with a per-(row,step) counter barrier.
__global__ __launch_bounds__(512, 2)
void rnn_scan_persist(const __hip_bfloat16* __restrict__ xh,
                      const uint4* __restrict__ Wp4,   // packed [k/8][j][k%8]
                      unsigned* __restrict__ hs_u32,   // hs as bf16x2 words
                      unsigned* __restrict__ ctr) {    // [64][1024], zeroed
    __shared__ __align__(16) float h_f[HID];
    __shared__ float red[PSPLIT][JSLICE];

    const int tid = threadIdx.x;
    const int b = blockIdx.x & 63;        // batch row
    const int p = blockIdx.x >> 6;        // hidden slice (64 apart -> same XCD)
    const int j0 = p * JSLICE;
    const int j = tid & (JSLICE - 1);     // 0..127 column within slice
    const int q = tid >> 7;               // 0..3 k-quarter

    // --- load W slice into registers, pre-unpacked to f32 ---
    float w[128];
#pragma unroll
    for (int g2 = 0; g2 < 16; ++g2) {
        uint4 wv = Wp4[(size_t)((q * 16 + g2) * HID + j0 + j)];
        w[g2 * 8 + 0] = bf16lo(wv.x);
        w[g2 * 8 + 1] = bf16hi(wv.x);
        w[g2 * 8 + 2] = bf16lo(wv.y);
        w[g2 * 8 + 3] = bf16hi(wv.y);
        w[g2 * 8 + 4] = bf16lo(wv.z);
        w[g2 * 8 + 5] = bf16hi(wv.z);
        w[g2 * 8 + 6] = bf16lo(wv.w);
        w[g2 * 8 + 7] = bf16hi(wv.w);
    }

    h_f[tid] = 0.f;                        // tid < 512 == HID
    __syncthreads();

    unsigned* myctr = ctr + b * TSTEPS;
    const size_t rowbase = (size_t)b * TSTEPS;

    for (int t = 0; t < TSTEPS; ++t) {
        // partial dot over k in [q*128, q*128+128)
        float acc = 0.f;
        const float4* hv = (const float4*)(h_f + q * 128);
#pragma unroll
        for (int g2 = 0; g2 < 16; ++g2) {
            float4 ha = hv[g2 * 2];
            float4 hb = hv[g2 * 2 + 1];
            acc += ha.x * w[g2 * 8 + 0];
            acc += ha.y * w[g2 * 8 + 1];
            acc += ha.z * w[g2 * 8 + 2];
            acc += ha.w * w[g2 * 8 + 3];
            acc += hb.x * w[g2 * 8 + 4];
            acc += hb.y * w[g2 * 8 + 5];
            acc += hb.z * w[g2 * 8 + 6];
            acc += hb.w * w[g2 * 8 + 7];
        }
        red[q][j] = acc;
        __syncthreads();                   // (A) partials ready; h reads done

        if (tid < JSLICE) {
            float xv = __bfloat162float(xh[(rowbase + t) * HID + j0 + tid]);
            float s = red[0][tid] + red[1][tid] + red[2][tid] + red[3][tid] + xv;
            float hn = tanhf(s);
            unsigned bbits = bf16bits(hn);
            unsigned nb = __shfl_down(bbits, 1);   // pair within wave
            if ((tid & 1) == 0) {
                unsigned packed = bbits | (nb << 16);
                __hip_atomic_store(
                    &hs_u32[(rowbase + t) * 256 + (j0 >> 1) + (tid >> 1)],
                    packed, __ATOMIC_RELAXED, __HIP_MEMORY_SCOPE_AGENT);
            }
        }

        if (t == TSTEPS - 1) break;        // no one waits on the last step

        __syncthreads();                   // (B) per-wave vmcnt drain of stores

        if (tid == 0) {
            __hip_atomic_fetch_add(&myctr[t], 1u, __ATOMIC_ACQ_REL,
                                   __HIP_MEMORY_SCOPE_AGENT);
            while (__hip_atomic_load(&myctr[t], __ATOMIC_ACQUIRE,
                                     __HIP_MEMORY_SCOPE_AGENT) < PSPLIT) {
                __builtin_amdgcn_s_sleep(1);
            }
        }
        __syncthreads();                   // (C) all waves see barrier passed

        if (tid < 256) {
            unsigned u = __hip_atomic_load(&hs_u32[(rowbase + t) * 256 + tid],
                                           __ATOMIC_RELAXED,
                                           __HIP_MEMORY_SCOPE_AGENT);
            h_f[2 * tid]     = __uint_as_float(u << 16);
            h_f[2 * tid + 1] = __uint_as_float(u & 0xffff0000u);
        }
        __syncthreads();                   // (D) h ready for next step
    }
}

extern "C" void kernel_launch(void* const* d_in, const int* in_sizes, int n_in,
                              void* d_out, int out_size, void* d_ws, size_t ws_size,
                              hipStream_t stream) {
    const float* x    = (const float*)d_in[0];   // [64,1024,256]
    const float* W_xh = (const float*)d_in[1];   // [256,512]
    const float* W_hh = (const float*)d_in[2];   // [512,512]
    const float* b_h  = (const float*)d_in[3];   // [512]
    const float* W_hy = (const float*)d_in[4];   // [512,256]
    const float* b_y  = (const float*)d_in[5];   // [256]
    float* out = (float*)d_out;                  // [64,1024,256]

    char* ws = (char*)d_ws;
    const size_t off_xh  = (size_t)1 << 20;
    const size_t off_hs  = off_xh + (size_t)BT * HID * 2;   // +64 MiB
    const size_t off_ctr = off_hs + (size_t)BT * HID * 2;   // +64 MiB

    __hip_bfloat16* Wp = (__hip_bfloat16*)ws;
    __hip_bfloat16* xh = (__hip_bfloat16*)(ws + off_xh);
    __hip_bfloat16* hs = (__hip_bfloat16*)(ws + off_hs);
    unsigned*      ctr = (unsigned*)(ws + off_ctr);

    // 0) zero the barrier counters (ws is poisoned 0xAA before every launch)
    hipMemsetAsync(ctr, 0, (size_t)NBATCH * TSTEPS * sizeof(unsigned), stream);

    // 1) pack W_hh -> bf16 grouped layout
    pack_whh_kernel<<<dim3(HID), dim3(HID), 0, stream>>>(W_hh, Wp);

    // 2) xh = x @ W_xh + b_h   (f32 A -> bf16 C)
    gemm_bias_kernel<float, __hip_bfloat16>
        <<<dim3(BT / 64, HID / 64), dim3(256), 0, stream>>>(x, W_xh, b_h, xh, BT, HID, NIN);

    // 3) persistent scan: 256 WGs, 1 per CU
    rnn_scan_persist<<<dim3(NBATCH * PSPLIT), dim3(512), 0, stream>>>(
        xh, (const uint4*)Wp, (unsigned*)hs, ctr);

    // 4) out = hs @ W_hy + b_y   (bf16 A -> f32 C)
    gemm_bias_kernel<__hip_bfloat16, float>
        <<<dim3(BT / 64, NOUT / 64), dim3(256), 0, stream>>>(hs, W_hy, b_y, out, BT, NOUT, HID);
}

// Round 3
// 3355.466 us; speedup vs baseline: 2.3044x; 2.0441x over previous
//
#include <hip/hip_runtime.h>
#include <hip/hip_bf16.h>
#include <hip/hip_fp16.h>

// Problem: B=64, T=1024, INPUT=256, HIDDEN=512, OUTPUT=256
//   xh = x @ W_xh + b_h
//   h_t = tanh(h_{t-1} @ W_hh + xh_t)   (serial over t)
//   out = hs @ W_hy + b_y
//
// Scan strategy (round 2): ONE CU per batch row, zero cross-WG traffic.
// Each thread owns 4 columns x 128-k-slice: 3 columns of f16 weights in
// registers (192 VGPRs), the 4th streamed from L2 each step. h in LDS
// (f16, double-buffered), k-reduction via shfl_xor butterflies.

#define BT 65536      // B*T
#define HID 512
#define NIN 256
#define NOUT 256
#define TSTEPS 1024
#define NBATCH 64

typedef _Float16 hf2_t __attribute__((ext_vector_type(2)));

__device__ __forceinline__ float fdot2(unsigned w, unsigned h, float acc) {
#if __has_builtin(__builtin_amdgcn_fdot2)
    return __builtin_amdgcn_fdot2(__builtin_bit_cast(hf2_t, w),
                                  __builtin_bit_cast(hf2_t, h), acc, false);
#else
    __half2 wv = __builtin_bit_cast(__half2, w);
    __half2 hv = __builtin_bit_cast(__half2, h);
    float2 wf = __half22float2(wv);
    float2 hf = __half22float2(hv);
    return acc + wf.x * hf.x + wf.y * hf.y;
#endif
}

__device__ __forceinline__ float dot4(uint4 w, uint4 h, float acc) {
    acc = fdot2(w.x, h.x, acc);
    acc = fdot2(w.y, h.y, acc);
    acc = fdot2(w.z, h.z, acc);
    acc = fdot2(w.w, h.w, acc);
    return acc;
}

__device__ __forceinline__ unsigned pack2h(float a, float b) {
    unsigned lo = (unsigned)__half_as_ushort(__float2half_rn(a));
    unsigned hi = (unsigned)__half_as_ushort(__float2half_rn(b));
    return lo | (hi << 16);
}

// ---------- generic load/store helpers ----------
__device__ __forceinline__ float4 load4f(const float* p) {
    return *(const float4*)p;
}
__device__ __forceinline__ float4 load4f(const __half* p) {
    ushort4 u = *(const ushort4*)p;
    float4 r;
    r.x = __half2float(__ushort_as_half(u.x));
    r.y = __half2float(__ushort_as_half(u.y));
    r.z = __half2float(__ushort_as_half(u.z));
    r.w = __half2float(__ushort_as_half(u.w));
    return r;
}
__device__ __forceinline__ void store1(float* p, float v) { *p = v; }
__device__ __forceinline__ void store1(__half* p, float v) { *p = __float2half_rn(v); }

// ---------- pack W_hh (f32 [k][j]) into per-thread f16 blobs ----------
// Thread t of the scan kernel: q=t>>2, s=t&3, k-range [128s,128s+128),
// columns 4q..4q+3. Cols 0-2 -> reg_blob[i][t] (i=0..47 uint4, coalesced),
// col 3 -> gcol_blob[j][t] (j=0..15 uint4, streamed from L2 per step).
__global__ __launch_bounds__(256)
void pack_w_kernel(const float* __restrict__ W,
                   unsigned* __restrict__ reg_blob,
                   unsigned* __restrict__ gcol_blob) {
    int t = blockIdx.x;      // 0..511  (scan thread id)
    int w = threadIdx.x;     // 0..255  (word index)
    int q = t >> 2, s = t & 3, k0 = 128 * s;
    if (w < 192) {
        int c = w >> 6, m = w & 63;
        int col = 4 * q + c, k = k0 + 2 * m;
        unsigned val = pack2h(W[(size_t)k * HID + col], W[(size_t)(k + 1) * HID + col]);
        int i = w >> 2, u = w & 3;
        reg_blob[i * 2048 + t * 4 + u] = val;
    } else {
        int m = w - 192;                       // 0..63
        int col = 4 * q + 3, k = k0 + 2 * m;
        unsigned val = pack2h(W[(size_t)k * HID + col], W[(size_t)(k + 1) * HID + col]);
        int j = m >> 2, u = m & 3;
        gcol_blob[j * 2048 + t * 4 + u] = val;
    }
}

// ---------- generic tiled GEMM with bias: C[M,N] = A[M,K] @ B[K,N] + bias[N] ----------
template <typename AT, typename CT>
__global__ __launch_bounds__(256)
void gemm_bias_kernel(const AT* __restrict__ A, const float* __restrict__ B,
                      const float* __restrict__ bias, CT* __restrict__ C,
                      int M, int N, int K) {
    const int TM = 64, TN = 64, TK = 16;
    __shared__ float As[TK][TM];
    __shared__ float Bs[TK][TN + 4];

    int tid = threadIdx.x;
    int tx = tid & 15;
    int ty = tid >> 4;
    int row0 = blockIdx.x * TM;
    int col0 = blockIdx.y * TN;

    float c[4][4];
#pragma unroll
    for (int i = 0; i < 4; ++i)
#pragma unroll
        for (int j = 0; j < 4; ++j) c[i][j] = 0.f;

    for (int kk = 0; kk < K; kk += TK) {
        {
            int ar = tid >> 2;
            int ac = (tid & 3) * 4;
            float4 av = load4f(A + (size_t)(row0 + ar) * K + kk + ac);
            As[ac + 0][ar] = av.x;
            As[ac + 1][ar] = av.y;
            As[ac + 2][ar] = av.z;
            As[ac + 3][ar] = av.w;
        }
        {
            int br = tid >> 4;
            int bc = (tid & 15) * 4;
            float4 bv = *(const float4*)(B + (size_t)(kk + br) * N + col0 + bc);
            *(float4*)&Bs[br][bc] = bv;
        }
        __syncthreads();
#pragma unroll
        for (int k = 0; k < TK; ++k) {
            float4 a = *(const float4*)&As[k][ty * 4];
            float4 b = *(const float4*)&Bs[k][tx * 4];
            float av[4] = {a.x, a.y, a.z, a.w};
            float bv[4] = {b.x, b.y, b.z, b.w};
#pragma unroll
            for (int i = 0; i < 4; ++i)
#pragma unroll
                for (int j = 0; j < 4; ++j) c[i][j] += av[i] * bv[j];
        }
        __syncthreads();
    }

#pragma unroll
    for (int j = 0; j < 4; ++j) {
        float bb = bias[col0 + tx * 4 + j];
#pragma unroll
        for (int i = 0; i < 4; ++i) {
            int r = row0 + ty * 4 + i;
            int cc = col0 + tx * 4 + j;
            store1(&C[(size_t)r * N + cc], c[i][j] + bb);
        }
    }
}

// ---------- scan: one WG (one CU) per batch row, no inter-WG traffic ----------
__global__ __launch_bounds__(512, 2)
void rnn_scan_single(const __half* __restrict__ xh,
                     const uint4* __restrict__ reg_blob,    // [48][512]
                     const uint4* __restrict__ gcol_blob,   // [16][512]
                     __half* __restrict__ hs) {
    // h double-buffered; 272B slice stride keeps the 4 per-wave broadcast
    // addresses on disjoint bank quads.
    __shared__ __align__(16) __half hbuf[2][4][136];

    const int t = threadIdx.x;
    const int b = blockIdx.x;
    const int s = t & 3;

    // 192 VGPRs of weights: columns 4q+0..2, k in [128s, 128s+128)
    uint4 W[48];
#pragma unroll
    for (int i = 0; i < 48; ++i) W[i] = reg_blob[i * 512 + t];

    hbuf[0][t >> 7][t & 127] = __ushort_as_half((unsigned short)0);
    hbuf[1][t >> 7][t & 127] = __ushort_as_half((unsigned short)0);
    __syncthreads();

    const __half* xp = xh + (size_t)b * TSTEPS * HID + t;
    __half* hp = hs + (size_t)b * TSTEPS * HID + t;
    const uint4* gb = gcol_blob + t;

    int cur = 0;
    __half prev = __ushort_as_half((unsigned short)0);

    for (int step = 0; step < TSTEPS; ++step) {
        float xv = __half2float(xp[(size_t)step * HID]);   // issued early, used late
        if (step) hp[(size_t)(step - 1) * HID] = prev;     // delayed store: far from barrier

        const uint4* hv = (const uint4*)&hbuf[cur][s][0];
        float a0 = 0.f, a1 = 0.f, a2 = 0.f, a3 = 0.f;

        // streamed column (col 4q+3) from L2, chunked with register-column dots
#pragma unroll
        for (int ch = 0; ch < 4; ++ch) {
            uint4 g0 = gb[(ch * 4 + 0) * 512];
            uint4 g1 = gb[(ch * 4 + 1) * 512];
            uint4 g2 = gb[(ch * 4 + 2) * 512];
            uint4 g3 = gb[(ch * 4 + 3) * 512];
            uint4 h0 = hv[ch * 4 + 0];
            uint4 h1 = hv[ch * 4 + 1];
            uint4 h2 = hv[ch * 4 + 2];
            uint4 h3 = hv[ch * 4 + 3];
            a0 = dot4(W[ch * 4 + 0], h0, a0);
            a1 = dot4(W[16 + ch * 4 + 0], h0, a1);
            a2 = dot4(W[32 + ch * 4 + 0], h0, a2);
            a0 = dot4(W[ch * 4 + 1], h1, a0);
            a1 = dot4(W[16 + ch * 4 + 1], h1, a1);
            a2 = dot4(W[32 + ch * 4 + 1], h1, a2);
            a0 = dot4(W[ch * 4 + 2], h2, a0);
            a1 = dot4(W[16 + ch * 4 + 2], h2, a1);
            a2 = dot4(W[32 + ch * 4 + 2], h2, a2);
            a0 = dot4(W[ch * 4 + 3], h3, a0);
            a1 = dot4(W[16 + ch * 4 + 3], h3, a1);
            a2 = dot4(W[32 + ch * 4 + 3], h3, a2);
            a3 = dot4(g0, h0, a3);
            a3 = dot4(g1, h1, a3);
            a3 = dot4(g2, h2, a3);
            a3 = dot4(g3, h3, a3);
        }

        // reduce across the 4 k-slices (lanes 4q..4q+3)
        a0 += __shfl_xor(a0, 1); a0 += __shfl_xor(a0, 2);
        a1 += __shfl_xor(a1, 1); a1 += __shfl_xor(a1, 2);
        a2 += __shfl_xor(a2, 1); a2 += __shfl_xor(a2, 2);
        a3 += __shfl_xor(a3, 1); a3 += __shfl_xor(a3, 2);
        float tot = (s == 0) ? a0 : (s == 1) ? a1 : (s == 2) ? a2 : a3;

        float hn = tanhf(tot + xv);
        prev = __float2half_rn(hn);
        hbuf[cur ^ 1][t >> 7][t & 127] = prev;
        __syncthreads();
        cur ^= 1;
    }
    hp[(size_t)(TSTEPS - 1) * HID] = prev;
}

extern "C" void kernel_launch(void* const* d_in, const int* in_sizes, int n_in,
                              void* d_out, int out_size, void* d_ws, size_t ws_size,
                              hipStream_t stream) {
    const float* x    = (const float*)d_in[0];   // [64,1024,256]
    const float* W_xh = (const float*)d_in[1];   // [256,512]
    const float* W_hh = (const float*)d_in[2];   // [512,512]
    const float* b_h  = (const float*)d_in[3];   // [512]
    const float* W_hy = (const float*)d_in[4];   // [512,256]
    const float* b_y  = (const float*)d_in[5];   // [256]
    float* out = (float*)d_out;                  // [64,1024,256]

    char* ws = (char*)d_ws;
    const size_t off_gcol = 48 * 512 * 16;                  // 384 KiB
    const size_t off_xh   = (size_t)1 << 20;                // 1 MiB
    const size_t off_hs   = off_xh + (size_t)BT * HID * 2;  // +64 MiB

    unsigned* reg_blob  = (unsigned*)ws;
    unsigned* gcol_blob = (unsigned*)(ws + off_gcol);
    __half*   xh        = (__half*)(ws + off_xh);
    __half*   hs        = (__half*)(ws + off_hs);

    // 1) pack W_hh -> per-thread f16 blobs
    pack_w_kernel<<<dim3(512), dim3(256), 0, stream>>>(W_hh, reg_blob, gcol_blob);

    // 2) xh = x @ W_xh + b_h   (f32 A -> f16 C)
    gemm_bias_kernel<float, __half>
        <<<dim3(BT / 64, HID / 64), dim3(256), 0, stream>>>(x, W_xh, b_h, xh, BT, HID, NIN);

    // 3) scan: 64 WGs, one per batch row, zero cross-WG traffic
    rnn_scan_single<<<dim3(NBATCH), dim3(512), 0, stream>>>(
        xh, (const uint4*)reg_blob, (const uint4*)gcol_blob, hs);

    // 4) out = hs @ W_hy + b_y   (f16 A -> f32 C)
    gemm_bias_kernel<__half, float>
        <<<dim3(BT / 64, NOUT / 64), dim3(256), 0, stream>>>(hs, W_hy, b_y, out, BT, NOUT, HID);
}